// Round 6
// baseline (368.023 us; speedup 1.0000x reference)
//
#include <hip/hip_runtime.h>

// AttentionBiasHead: B=32, L=512, DIM_IN=512, DQ=DK=128, DS=256, DMLP=128
// Round 13:
//   - mid/proj: REVERT to r9 both-LDS staging (Xs+Ws, 27.6 KB). Evidence:
//     r9=105us vs r10(W-only)=125 / r11+r12(X-only)=118-122. Global operand
//     fragments put L2 latency inside the MFMA loop; both tiles want LDS.
//   - attn4: new 4-group attention. 512 blocks x 512 thr; block = 32 q-rows;
//     4 key-groups x 2 waves (128 keys each). S halves to 32 VGPR ->
//     target <=128 VGPR -> 4 waves/SIMD -> 2 blocks/CU (was 1). K/V frags
//     direct from global (L2-hot), no K/V staging, ~6 barriers + combine.
//     P/bias in LDS (70.7 KB). 4-way softmax combine via redm/reds[4][32].
// prep / bias2 / canon unchanged (r12).

typedef unsigned int   u32;
typedef unsigned short u16;
typedef __attribute__((ext_vector_type(8))) short bf16x8;   // 8 bf16 = 4 VGPR
typedef __attribute__((ext_vector_type(4))) float f32x4;
typedef __attribute__((ext_vector_type(4))) u32   u32x4;    // 16B = 8 u16

__device__ __forceinline__ float B2F(u16 x) { return __uint_as_float(((u32)x) << 16); }
__device__ __forceinline__ u16 f2bf(float f) {
    u32 u = __float_as_uint(f);
    return (u16)((u + 0x7fffu + ((u >> 16) & 1u)) >> 16);   // RNE
}

// ---------------------------------------------------------------------------
// prep: [0,detN) detect(x16) | [detN,detN+24) wtrans | [detN+24,detN+40) mlp1
// ---------------------------------------------------------------------------
__global__ __launch_bounds__(256) void prep(
    const void* __restrict__ mask, u32* __restrict__ flag, int detN,
    const float* __restrict__ Wq, const float* __restrict__ Wk, const float* __restrict__ Wv,
    u16* __restrict__ WT,
    const float* __restrict__ sf, const float* __restrict__ Wb1,
    const float* __restrict__ bb1, float* __restrict__ hT)
{
    __shared__ u16 Ts[64][136];
    const int blk = blockIdx.x, tid = threadIdx.x;

    if (blk < detN) {
        const u32* m = (const u32*)mask;
        u32 any = 0;
#pragma unroll
        for (int it = 0; it < 16; ++it) {
            const size_t t = ((size_t)blk * 16 + it) * 256 + tid;
#pragma unroll
            for (int l = 0; l < 4; ++l) any |= (m[t * 4 + l] > 1u) ? 1u : 0u;
        }
        if (__ballot(any)) {
            if ((tid & 63) == 0) atomicOr(flag, 1u);
        }
        return;
    }
    if (blk < detN + 24) {
        const int widx = blk - detN;
        const int s = widx >> 3, kt = widx & 7;
        const float* W = (s == 0) ? Wq : (s == 1) ? Wk : Wv;
        {
            const int kk = tid >> 2, nseg = tid & 3;
            const float4* src = (const float4*)(W + (size_t)(kt * 64 + kk) * 128 + nseg * 32);
#pragma unroll
            for (int j = 0; j < 8; ++j) {
                float4 v = src[j];
                Ts[kk][nseg * 32 + j * 4 + 0] = f2bf(v.x);
                Ts[kk][nseg * 32 + j * 4 + 1] = f2bf(v.y);
                Ts[kk][nseg * 32 + j * 4 + 2] = f2bf(v.z);
                Ts[kk][nseg * 32 + j * 4 + 3] = f2bf(v.w);
            }
        }
        __syncthreads();
        {
            const int n = tid >> 1, kseg = tid & 1;
            u32 pk[16];
#pragma unroll
            for (int j = 0; j < 16; ++j)
                pk[j] = (u32)Ts[kseg * 32 + 2 * j][n] | ((u32)Ts[kseg * 32 + 2 * j + 1][n] << 16);
            u32x4* dst = (u32x4*)(WT + (size_t)s * 65536 + (size_t)n * 512 + kt * 64 + kseg * 32);
            dst[0] = (u32x4){pk[0], pk[1], pk[2], pk[3]};
            dst[1] = (u32x4){pk[4], pk[5], pk[6], pk[7]};
            dst[2] = (u32x4){pk[8], pk[9], pk[10], pk[11]};
            dst[3] = (u32x4){pk[12], pk[13], pk[14], pk[15]};
        }
        return;
    }
    {
        // hT[m][b] = relu(sf @ Wb1 + bb1)^T
        const int t = (blk - detN - 24) * 256 + tid;   // 16 blocks -> 4096
        const int b = t >> 7, n = t & 127;
        float acc = bb1[n];
        for (int m = 0; m < 256; ++m)
            acc += sf[b * 256 + m] * Wb1[m * 128 + n];
        hT[n * 32 + b] = fmaxf(acc, 0.0f);
    }
}

// ---------------------------------------------------------------------------
// mid v5: [0,1024) bias2 | [1024,1792) proj(both-LDS, r9) | [1792,2048) canon
// ---------------------------------------------------------------------------
__global__ __launch_bounds__(256) void mid(
    const float* __restrict__ Xq, const float* __restrict__ Xk, const float* __restrict__ Xv,
    const u16* __restrict__ WT,
    const float* __restrict__ Bq, const float* __restrict__ Bk, const float* __restrict__ Bv,
    u16* __restrict__ Yq, u16* __restrict__ Yk, u16* __restrict__ YvT,
    const float* __restrict__ hT, const float* __restrict__ Wb2,
    const float* __restrict__ bb2, u16* __restrict__ biasb,
    const void* __restrict__ mask, const u32* __restrict__ flag, int mode,
    int docanon, unsigned char* __restrict__ canonbuf)
{
    __shared__ u16 Xs[64][72];     // 9216 B
    __shared__ u16 Ws[128][72];    // 18432 B
    const int blk = blockIdx.x, tid = threadIdx.x;

    if (blk < 1024) {
        // ---- bias = h^T @ Wb2 + bb2 -> bf16. 1 n x 32 b, unroll 16. ----
        const size_t n = (size_t)blk * 256 + tid;
        float acc[32];
        {
            const float bb = bb2[n];
#pragma unroll
            for (int b = 0; b < 32; ++b) acc[b] = bb;
        }
#pragma unroll 16
        for (int m = 0; m < 128; ++m) {
            const float wv = Wb2[(size_t)m * 262144 + n];
            const float* hrow = hT + m * 32;     // wave-uniform -> s_load
#pragma unroll
            for (int b = 0; b < 32; ++b) acc[b] += wv * hrow[b];
        }
#pragma unroll
        for (int b = 0; b < 32; ++b)
            biasb[(size_t)b * 262144 + n] = f2bf(acc[b]);
        return;
    }

    if (blk < 1792) {
        // ---- proj_mfma, both operands staged in LDS (r9 form) ----
        const int pidx = blk - 1024;
        const int s = pidx >> 8;
        const int R0 = (pidx & 255) * 64;
        const float* X; const float* Bi;
        if (s == 0)      { X = Xq; Bi = Bq; }
        else if (s == 1) { X = Xk; Bi = Bk; }
        else             { X = Xv; Bi = Bv; }
        const u16* Wn = WT + (size_t)s * 65536;

        const int w    = tid >> 6;
        const int lane = tid & 63;
        const int c    = lane & 15;
        const int qd   = lane >> 4;

        f32x4 acc[8];
#pragma unroll
        for (int t = 0; t < 8; ++t) acc[t] = (f32x4){0.f, 0.f, 0.f, 0.f};

        for (int kc = 0; kc < 8; ++kc) {
            __syncthreads();
            {   // stage X tile [64 rows][64 k] f32 -> bf16
                const int row = tid >> 2, seg = tid & 3;
                const float4* src = (const float4*)(X + (size_t)(R0 + row) * 512 + kc * 64 + seg * 16);
                float4 v0 = src[0], v1 = src[1], v2 = src[2], v3 = src[3];
                u32 pk[8];
                pk[0] = (u32)f2bf(v0.x) | ((u32)f2bf(v0.y) << 16);
                pk[1] = (u32)f2bf(v0.z) | ((u32)f2bf(v0.w) << 16);
                pk[2] = (u32)f2bf(v1.x) | ((u32)f2bf(v1.y) << 16);
                pk[3] = (u32)f2bf(v1.z) | ((u32)f2bf(v1.w) << 16);
                pk[4] = (u32)f2bf(v2.x) | ((u32)f2bf(v2.y) << 16);
                pk[5] = (u32)f2bf(v2.z) | ((u32)f2bf(v2.w) << 16);
                pk[6] = (u32)f2bf(v3.x) | ((u32)f2bf(v3.y) << 16);
                pk[7] = (u32)f2bf(v3.z) | ((u32)f2bf(v3.w) << 16);
                u32x4* dst = (u32x4*)&Xs[row][seg * 16];
                dst[0] = (u32x4){pk[0], pk[1], pk[2], pk[3]};
                dst[1] = (u32x4){pk[4], pk[5], pk[6], pk[7]};
            }
            {   // stage W tile [128 n][64 k] bf16
                const int n = tid >> 1, seg = tid & 1;
                const u32x4* src = (const u32x4*)(Wn + (size_t)n * 512 + kc * 64 + seg * 32);
                u32x4 v0 = src[0], v1 = src[1], v2 = src[2], v3 = src[3];
                u32x4* dst = (u32x4*)&Ws[n][seg * 32];
                dst[0] = v0; dst[1] = v1; dst[2] = v2; dst[3] = v3;
            }
            __syncthreads();

#pragma unroll
            for (int ks = 0; ks < 2; ++ks) {
                if (s < 2) {
                    const bf16x8 a = *(const bf16x8*)&Xs[w * 16 + c][ks * 32 + qd * 8];
#pragma unroll
                    for (int nt = 0; nt < 8; ++nt) {
                        const bf16x8 b = *(const bf16x8*)&Ws[nt * 16 + c][ks * 32 + qd * 8];
                        acc[nt] = __builtin_amdgcn_mfma_f32_16x16x32_bf16(a, b, acc[nt], 0, 0, 0);
                    }
                } else {
#pragma unroll
                    for (int t = 0; t < 2; ++t) {
                        const bf16x8 a = *(const bf16x8*)&Ws[(2 * w + t) * 16 + c][ks * 32 + qd * 8];
#pragma unroll
                        for (int it = 0; it < 4; ++it) {
                            const bf16x8 b = *(const bf16x8*)&Xs[it * 16 + c][ks * 32 + qd * 8];
                            acc[t * 4 + it] = __builtin_amdgcn_mfma_f32_16x16x32_bf16(a, b, acc[t * 4 + it], 0, 0, 0);
                        }
                    }
                }
            }
        }

        if (s < 2) {
            u16* Y = (s == 0) ? Yq : Yk;
#pragma unroll
            for (int nt = 0; nt < 8; ++nt) {
                const float bn = Bi[nt * 16 + c];
#pragma unroll
                for (int r = 0; r < 4; ++r)
                    Y[(size_t)(R0 + w * 16 + qd * 4 + r) * 128 + nt * 16 + c] = f2bf(acc[nt][r] + bn);
            }
        } else {
            const int bb = (pidx & 255) >> 3, il0 = R0 & 511;
#pragma unroll
            for (int t = 0; t < 2; ++t)
#pragma unroll
                for (int r = 0; r < 4; ++r) {
                    const int d = (2 * w + t) * 16 + qd * 4 + r;
                    const float bd = Bi[d];
#pragma unroll
                    for (int it = 0; it < 4; ++it)
                        YvT[(size_t)bb * 65536 + (size_t)d * 512 + il0 + it * 16 + c] =
                            f2bf(acc[t * 4 + it][r] + bd);
                }
        }
        return;
    }

    if (docanon) {
        // ---- mask_canon: 256 blocks, grid-stride 8 x 16 B per thread ----
        const int cb = blk - 1792;
        const bool i32src = (mode == 2) || (mode == 0 && *flag == 0);
#pragma unroll
        for (int it = 0; it < 8; ++it) {
            const size_t base = ((size_t)cb * 8 + it) * 4096 + (size_t)tid * 16;
            u32 wq[4];
            if (i32src) {
                const int* mi = (const int*)mask + base;
#pragma unroll
                for (int q = 0; q < 4; ++q) {
                    const int4 v = *(const int4*)(mi + q * 4);
                    wq[q] = (v.x ? 1u : 0u) | ((v.y ? 1u : 0u) << 8)
                          | ((v.z ? 1u : 0u) << 16) | ((v.w ? 1u : 0u) << 24);
                }
            } else {
                const u32x4 v = *(const u32x4*)((const unsigned char*)mask + base);
#pragma unroll
                for (int q = 0; q < 4; ++q) {
                    const u32 x = v[q];
                    wq[q] = (((x & 0x7F7F7F7Fu) + 0x7F7F7F7Fu) | x) >> 7 & 0x01010101u;
                }
            }
            *(u32x4*)(canonbuf + base) = (u32x4){wq[0], wq[1], wq[2], wq[3]};
        }
    }
}

// ---------------------------------------------------------------------------
// attn4: 512 blocks x 512 thr. Block = (bb, it) -> 32 q-rows. 4 key-groups
// x 2 waves; group g owns keys [g*128, g*128+128). K/V frags direct from
// global (L2-hot). P/bias in LDS. 4-way softmax combine. Target <=128 VGPR.
// ---------------------------------------------------------------------------
__global__ __launch_bounds__(512, 4) void attn4(
    const u16* __restrict__ qb, const u16* __restrict__ kb, const u16* __restrict__ vTb,
    const unsigned char* __restrict__ canon, const u16* __restrict__ biasb,
    float* __restrict__ out)
{
    __shared__ alignas(16) u16 Ps[4][32 * 136];   // 34816 B (Oc aliases later)
    __shared__ alignas(16) u16 Bs[4][32 * 136];   // 34816 B
    __shared__ float redm[4][32];
    __shared__ float reds[4][32];
    // total ~70.7 KiB -> 2 blocks/CU

    const int tid  = threadIdx.x;
    const int g    = tid >> 7;          // key group 0..3
    const int gt   = tid & 127;
    const int wl   = (tid >> 6) & 1;    // wave in group
    const int lane = tid & 63;
    const int c    = lane & 15;
    const int qd   = lane >> 4;
    const int bb   = blockIdx.x & 31;   // XCD-coherent decode
    const int it   = blockIdx.x >> 5;   // 0..15
    const int i0   = it * 32;

    // ---- Q fragments (rows i0 + wl*16 + c) -----------------------------
    bf16x8 qf[4];
    {
        const u16* qp = qb + ((size_t)bb * 512 + i0 + wl * 16 + c) * 128 + qd * 8;
#pragma unroll
        for (int kc = 0; kc < 4; ++kc) qf[kc] = *(const bf16x8*)(qp + kc * 32);
    }

    // ---- QK^T: keys g*128 + jt*64 + jj*16 + c, K frags from global ------
    f32x4 S[2][4];
#pragma unroll
    for (int jt = 0; jt < 2; ++jt)
#pragma unroll
        for (int jj = 0; jj < 4; ++jj) S[jt][jj] = (f32x4){0.f, 0.f, 0.f, 0.f};

    const u16* kgb = kb + ((size_t)bb * 512 + g * 128) * 128;
#pragma unroll
    for (int jt = 0; jt < 2; ++jt)
#pragma unroll
        for (int kc = 0; kc < 4; ++kc) {
            const bf16x8 a = qf[kc];
#pragma unroll
            for (int jj = 0; jj < 4; ++jj) {
                const bf16x8 b = *(const bf16x8*)(kgb + (size_t)(jt * 64 + jj * 16 + c) * 128
                                                  + kc * 32 + qd * 8);
                S[jt][jj] = __builtin_amdgcn_mfma_f32_16x16x32_bf16(a, b, S[jt][jj], 0, 0, 0);
            }
        }

    // ---- bias prefetch (overlaps softmax) ------------------------------
    const int brow = gt >> 2, bseg = gt & 3;
    u32x4 bq0, bq1, bq2, bq3;
    {
        const u32x4* sb = (const u32x4*)(biasb + (size_t)bb * 262144
                          + (size_t)(i0 + brow) * 512 + g * 128 + bseg * 32);
        bq0 = sb[0]; bq1 = sb[1];
        const u32x4* sb2 = (const u32x4*)(biasb + (size_t)bb * 262144
                           + (size_t)(i0 + brow) * 512 + g * 128 + bseg * 32 + 16);
        bq2 = sb2[0]; bq3 = sb2[1];
    }

    // ---- softmax: group-local then 4-way combine -----------------------
    const float sc = 0.08838834764831845f;
    float lm[4];
#pragma unroll
    for (int r = 0; r < 4; ++r) {
        const int lrow = wl * 16 + qd * 4 + r;
        const unsigned char* cp = canon + ((size_t)bb * 512 + i0 + lrow) * 512 + g * 128;
        float mx = -3.4e38f;
#pragma unroll
        for (int jt = 0; jt < 2; ++jt)
#pragma unroll
            for (int jj = 0; jj < 4; ++jj) {
                float s = S[jt][jj][r] * sc;
                if (cp[jt * 64 + jj * 16 + c]) s = 1e-9f;
                S[jt][jj][r] = s;
                mx = fmaxf(mx, s);
            }
#pragma unroll
        for (int o = 1; o < 16; o <<= 1) mx = fmaxf(mx, __shfl_xor(mx, o, 64));
        lm[r] = mx;
    }
    if (c == 0) {
#pragma unroll
        for (int r = 0; r < 4; ++r) redm[g][wl * 16 + qd * 4 + r] = lm[r];
    }
    __syncthreads();
    float ls[4];
#pragma unroll
    for (int r = 0; r < 4; ++r) {
        const int lrow = wl * 16 + qd * 4 + r;
        const float gmx = fmaxf(fmaxf(redm[0][lrow], redm[1][lrow]),
                                fmaxf(redm[2][lrow], redm[3][lrow]));
        float sm = 0.f;
#pragma unroll
        for (int jt = 0; jt < 2; ++jt)
#pragma unroll
            for (int jj = 0; jj < 4; ++jj) {
                const float e = __expf(S[jt][jj][r] - gmx);
                S[jt][jj][r] = e;
                sm += e;
            }
#pragma unroll
        for (int o = 1; o < 16; o <<= 1) sm += __shfl_xor(sm, o, 64);
        ls[r] = sm;
    }
    if (c == 0) {
#pragma unroll
        for (int r = 0; r < 4; ++r) reds[g][wl * 16 + qd * 4 + r] = ls[r];
    }
    __syncthreads();
    float inv_[4];
#pragma unroll
    for (int r = 0; r < 4; ++r) {
        const int lrow = wl * 16 + qd * 4 + r;
        inv_[r] = 1.0f / (reds[0][lrow] + reds[1][lrow] + reds[2][lrow] + reds[3][lrow]);
    }

    // ---- write Bs from prefetched regs, then P --------------------------
    {
        u32x4* db = (u32x4*)&Bs[g][brow * 136 + bseg * 32];
        db[0] = bq0; db[1] = bq1; db[2] = bq2; db[3] = bq3;
    }
    __syncthreads();
#pragma unroll
    for (int r = 0; r < 4; ++r) {
        const int lrow = wl * 16 + qd * 4 + r;
#pragma unroll
        for (int jt = 0; jt < 2; ++jt)
#pragma unroll
            for (int jj = 0; jj < 4; ++jj) {
                const float p = S[jt][jj][r] * inv_[r]
                              + B2F(Bs[g][lrow * 136 + jt * 64 + jj * 16 + c]);
                Ps[g][lrow * 136 + jt * 64 + jj * 16 + c] = f2bf(p);
            }
    }
    __syncthreads();

    // ---- PV: A from Ps (LDS), V frags direct from global ----------------
    f32x4 O_[8];
#pragma unroll
    for (int ns = 0; ns < 8; ++ns) O_[ns] = (f32x4){0.f, 0.f, 0.f, 0.f};

    const u16* vgb = vTb + (size_t)bb * 65536 + g * 128;
#pragma unroll
    for (int kc = 0; kc < 4; ++kc) {
        const bf16x8 a = *(const bf16x8*)&Ps[g][(wl * 16 + c) * 136 + kc * 32 + qd * 8];
#pragma unroll
        for (int ns = 0; ns < 8; ++ns) {
            const bf16x8 b = *(const bf16x8*)(vgb + (size_t)(ns * 16 + c) * 512
                                              + kc * 32 + qd * 8);
            O_[ns] = __builtin_amdgcn_mfma_f32_16x16x32_bf16(a, b, O_[ns], 0, 0, 0);
        }
    }

    // ---- 4-way O combine in LDS (aliases dead Ps), coalesced store ------
    __syncthreads();
    float* Oc = (float*)&Ps[0][0];   // 16 KB needed, 34.8 KB available
    if (g == 3) {
#pragma unroll
        for (int ns = 0; ns < 8; ++ns)
#pragma unroll
            for (int r = 0; r < 4; ++r)
                Oc[(wl * 16 + qd * 4 + r) * 128 + ns * 16 + c] = O_[ns][r];
    }
    __syncthreads();
    if (g == 2) {
#pragma unroll
        for (int ns = 0; ns < 8; ++ns)
#pragma unroll
            for (int r = 0; r < 4; ++r)
                Oc[(wl * 16 + qd * 4 + r) * 128 + ns * 16 + c] += O_[ns][r];
    }
    __syncthreads();
    if (g == 1) {
#pragma unroll
        for (int ns = 0; ns < 8; ++ns)
#pragma unroll
            for (int r = 0; r < 4; ++r)
                Oc[(wl * 16 + qd * 4 + r) * 128 + ns * 16 + c] += O_[ns][r];
    }
    __syncthreads();
    if (g == 0) {
#pragma unroll
        for (int ns = 0; ns < 8; ++ns)
#pragma unroll
            for (int r = 0; r < 4; ++r)
                Oc[(wl * 16 + qd * 4 + r) * 128 + ns * 16 + c] += O_[ns][r];
    }
    __syncthreads();
    {
        const int row = tid >> 4, sg = tid & 15;   // 32 rows x 16 segs x 8 f32
        const float4* s4 = (const float4*)&Oc[row * 128 + sg * 8];
        float4* d4 = (float4*)(out + ((size_t)bb * 512 + i0 + row) * 128 + sg * 8);
        d4[0] = s4[0]; d4[1] = s4[1];
    }
}

// ---------------------------------------------------------------------------
extern "C" void kernel_launch(void* const* d_in, const int* in_sizes, int n_in,
                              void* d_out, int out_size, void* d_ws, size_t ws_size,
                              hipStream_t stream)
{
    const float* query = (const float*)d_in[0];
    const float* key_  = (const float*)d_in[1];
    const float* value = (const float*)d_in[2];
    const float* sf    = (const float*)d_in[3];
    const void*  mask  = d_in[4];
    const float* Wq  = (const float*)d_in[5];
    const float* bq  = (const float*)d_in[6];
    const float* Wk  = (const float*)d_in[7];
    const float* bk  = (const float*)d_in[8];
    const float* Wv  = (const float*)d_in[9];
    const float* bv  = (const float*)d_in[10];
    const float* Wb1 = (const float*)d_in[11];
    const float* bb1 = (const float*)d_in[12];
    const float* Wb2 = (const float*)d_in[13];
    const float* bb2 = (const float*)d_in[14];
    float* out = (float*)d_out;

    // ws layout
    char* w = (char*)d_ws;
    u32*   flag     = (u32*)(w);                                // 4 B
    unsigned char* canonbuf = (unsigned char*)(w + (1u << 20)); // 8 MiB
    u16*   qb    = (u16*)(w + (16u << 20));                     // 4 MiB
    u16*   kb    = (u16*)(w + (24u << 20));                     // 4 MiB
    u16*   vTb   = (u16*)(w + (32u << 20));                     // 4 MiB
    float* hT    = (float*)(w + (40u << 20));                   // 16 KiB (hT[m][b])
    u16*   biasb = (u16*)(w + (41u << 20));                     // 16 MiB
    u16*   WT    = (u16*)(w + (58u << 20));                     // 384 KiB

    // Mask dtype: mode 0 = runtime detect, 1 = bool bytes direct, 2 = i32.
    int mode = 0;
    if (n_in >= 15 && in_sizes[0] == 33554432) {
        if (in_sizes[4] == 8388608)       mode = 1;
        else if (in_sizes[4] == 33554432) mode = 2;
    }
    if (mode == 0) hipMemsetAsync(flag, 0, 4, stream);

    const int detN = (mode == 0) ? 128 : 0;
    prep<<<detN + 40, 256, 0, stream>>>(mask, flag, detN, Wq, Wk, Wv, WT,
                                        sf, Wb1, bb1, hT);

    const int docanon = (mode != 1) ? 1 : 0;
    mid<<<2048, 256, 0, stream>>>(query, key_, value, WT,
                                  bq, bk, bv, qb, kb, vTb,
                                  hT, Wb2, bb2, biasb,
                                  mask, flag, mode, docanon, canonbuf);

    const unsigned char* canon = (mode == 1) ? (const unsigned char*)mask : canonbuf;
    attn4<<<512, 512, 0, stream>>>(qb, kb, vTb, canon, biasb, out);
}

// Round 7
// 348.551 us; speedup vs baseline: 1.0559x; 1.0559x over previous
//
#include <hip/hip_runtime.h>

// AttentionBiasHead: B=32, L=512, DIM_IN=512, DQ=DK=128, DS=256, DMLP=128
// Round 14:
//   - attn: REVERT to attn8 (round 8, proven best; attn4's global K/V frags
//     regressed ~20us -- MFMA operands want LDS staging + prefetch).
//   - mid/proj: both-LDS staging kept (proven r9/r13), BK 64->32:
//     Xs[64][40]+Ws[128][40] = 15.4 KB static LDS -> 8 blocks/CU for ALL
//     mid block types (was 5). Attacks the measured 29% occupancy.
//   - prep r12, bias2/canon r12 forms.

typedef unsigned int   u32;
typedef unsigned short u16;
typedef __attribute__((ext_vector_type(8))) short bf16x8;   // 8 bf16 = 4 VGPR
typedef __attribute__((ext_vector_type(4))) float f32x4;
typedef __attribute__((ext_vector_type(4))) u32   u32x4;    // 16B = 8 u16

__device__ __forceinline__ float B2F(u16 x) { return __uint_as_float(((u32)x) << 16); }
__device__ __forceinline__ u16 f2bf(float f) {
    u32 u = __float_as_uint(f);
    return (u16)((u + 0x7fffu + ((u >> 16) & 1u)) >> 16);   // RNE
}

// ---------------------------------------------------------------------------
// prep: [0,detN) detect(x16) | [detN,detN+24) wtrans | [detN+24,detN+40) mlp1
// ---------------------------------------------------------------------------
__global__ __launch_bounds__(256) void prep(
    const void* __restrict__ mask, u32* __restrict__ flag, int detN,
    const float* __restrict__ Wq, const float* __restrict__ Wk, const float* __restrict__ Wv,
    u16* __restrict__ WT,
    const float* __restrict__ sf, const float* __restrict__ Wb1,
    const float* __restrict__ bb1, float* __restrict__ hT)
{
    __shared__ u16 Ts[64][136];
    const int blk = blockIdx.x, tid = threadIdx.x;

    if (blk < detN) {
        const u32* m = (const u32*)mask;
        u32 any = 0;
#pragma unroll
        for (int it = 0; it < 16; ++it) {
            const size_t t = ((size_t)blk * 16 + it) * 256 + tid;
#pragma unroll
            for (int l = 0; l < 4; ++l) any |= (m[t * 4 + l] > 1u) ? 1u : 0u;
        }
        if (__ballot(any)) {
            if ((tid & 63) == 0) atomicOr(flag, 1u);
        }
        return;
    }
    if (blk < detN + 24) {
        const int widx = blk - detN;
        const int s = widx >> 3, kt = widx & 7;
        const float* W = (s == 0) ? Wq : (s == 1) ? Wk : Wv;
        {
            const int kk = tid >> 2, nseg = tid & 3;
            const float4* src = (const float4*)(W + (size_t)(kt * 64 + kk) * 128 + nseg * 32);
#pragma unroll
            for (int j = 0; j < 8; ++j) {
                float4 v = src[j];
                Ts[kk][nseg * 32 + j * 4 + 0] = f2bf(v.x);
                Ts[kk][nseg * 32 + j * 4 + 1] = f2bf(v.y);
                Ts[kk][nseg * 32 + j * 4 + 2] = f2bf(v.z);
                Ts[kk][nseg * 32 + j * 4 + 3] = f2bf(v.w);
            }
        }
        __syncthreads();
        {
            const int n = tid >> 1, kseg = tid & 1;
            u32 pk[16];
#pragma unroll
            for (int j = 0; j < 16; ++j)
                pk[j] = (u32)Ts[kseg * 32 + 2 * j][n] | ((u32)Ts[kseg * 32 + 2 * j + 1][n] << 16);
            u32x4* dst = (u32x4*)(WT + (size_t)s * 65536 + (size_t)n * 512 + kt * 64 + kseg * 32);
            dst[0] = (u32x4){pk[0], pk[1], pk[2], pk[3]};
            dst[1] = (u32x4){pk[4], pk[5], pk[6], pk[7]};
            dst[2] = (u32x4){pk[8], pk[9], pk[10], pk[11]};
            dst[3] = (u32x4){pk[12], pk[13], pk[14], pk[15]};
        }
        return;
    }
    {
        // hT[m][b] = relu(sf @ Wb1 + bb1)^T
        const int t = (blk - detN - 24) * 256 + tid;   // 16 blocks -> 4096
        const int b = t >> 7, n = t & 127;
        float acc = bb1[n];
        for (int m = 0; m < 256; ++m)
            acc += sf[b * 256 + m] * Wb1[m * 128 + n];
        hT[n * 32 + b] = fmaxf(acc, 0.0f);
    }
}

// ---------------------------------------------------------------------------
// mid v6: [0,1024) bias2 | [1024,1792) proj(both-LDS, BK=32) | [1792,2048) canon
// static LDS 15.4 KB -> 8 blocks/CU for all block types.
// ---------------------------------------------------------------------------
__global__ __launch_bounds__(256) void mid(
    const float* __restrict__ Xq, const float* __restrict__ Xk, const float* __restrict__ Xv,
    const u16* __restrict__ WT,
    const float* __restrict__ Bq, const float* __restrict__ Bk, const float* __restrict__ Bv,
    u16* __restrict__ Yq, u16* __restrict__ Yk, u16* __restrict__ YvT,
    const float* __restrict__ hT, const float* __restrict__ Wb2,
    const float* __restrict__ bb2, u16* __restrict__ biasb,
    const void* __restrict__ mask, const u32* __restrict__ flag, int mode,
    int docanon, unsigned char* __restrict__ canonbuf)
{
    __shared__ u16 Xs[64][40];     // 5120 B
    __shared__ u16 Ws[128][40];    // 10240 B
    const int blk = blockIdx.x, tid = threadIdx.x;

    if (blk < 1024) {
        // ---- bias = h^T @ Wb2 + bb2 -> bf16. 1 n x 32 b, unroll 16. ----
        const size_t n = (size_t)blk * 256 + tid;
        float acc[32];
        {
            const float bb = bb2[n];
#pragma unroll
            for (int b = 0; b < 32; ++b) acc[b] = bb;
        }
#pragma unroll 16
        for (int m = 0; m < 128; ++m) {
            const float wv = Wb2[(size_t)m * 262144 + n];
            const float* hrow = hT + m * 32;     // wave-uniform -> s_load
#pragma unroll
            for (int b = 0; b < 32; ++b) acc[b] += wv * hrow[b];
        }
#pragma unroll
        for (int b = 0; b < 32; ++b)
            biasb[(size_t)b * 262144 + n] = f2bf(acc[b]);
        return;
    }

    if (blk < 1792) {
        // ---- proj_mfma, both operands in LDS, BK=32, 16 kc phases ----
        const int pidx = blk - 1024;
        const int s = pidx >> 8;
        const int R0 = (pidx & 255) * 64;
        const float* X; const float* Bi;
        if (s == 0)      { X = Xq; Bi = Bq; }
        else if (s == 1) { X = Xk; Bi = Bk; }
        else             { X = Xv; Bi = Bv; }
        const u16* Wn = WT + (size_t)s * 65536;   // [n=128][k=512] bf16

        const int w    = tid >> 6;
        const int lane = tid & 63;
        const int c    = lane & 15;
        const int qd   = lane >> 4;

        f32x4 acc[8];
#pragma unroll
        for (int t = 0; t < 8; ++t) acc[t] = (f32x4){0.f, 0.f, 0.f, 0.f};

        for (int kc = 0; kc < 16; ++kc) {
            __syncthreads();
            {   // stage X tile [64 rows][32 k] f32 -> bf16; thread = 8 f32
                const int row = tid >> 2, seg = tid & 3;
                const float4* src = (const float4*)(X + (size_t)(R0 + row) * 512 + kc * 32 + seg * 8);
                float4 v0 = src[0], v1 = src[1];
                u32 pk[4];
                pk[0] = (u32)f2bf(v0.x) | ((u32)f2bf(v0.y) << 16);
                pk[1] = (u32)f2bf(v0.z) | ((u32)f2bf(v0.w) << 16);
                pk[2] = (u32)f2bf(v1.x) | ((u32)f2bf(v1.y) << 16);
                pk[3] = (u32)f2bf(v1.z) | ((u32)f2bf(v1.w) << 16);
                *(u32x4*)&Xs[row][seg * 8] = (u32x4){pk[0], pk[1], pk[2], pk[3]};
            }
            {   // stage W tile [128 n][32 k] bf16; thread = 16 u16 (32B)
                const int n = tid >> 1, seg = tid & 1;
                const u32x4* src = (const u32x4*)(Wn + (size_t)n * 512 + kc * 32 + seg * 16);
                u32x4 v0 = src[0], v1 = src[1];
                u32x4* dst = (u32x4*)&Ws[n][seg * 16];
                dst[0] = v0; dst[1] = v1;
            }
            __syncthreads();

            if (s < 2) {
                const bf16x8 a = *(const bf16x8*)&Xs[w * 16 + c][qd * 8];
#pragma unroll
                for (int nt = 0; nt < 8; ++nt) {
                    const bf16x8 b = *(const bf16x8*)&Ws[nt * 16 + c][qd * 8];
                    acc[nt] = __builtin_amdgcn_mfma_f32_16x16x32_bf16(a, b, acc[nt], 0, 0, 0);
                }
            } else {
#pragma unroll
                for (int t = 0; t < 2; ++t) {
                    const bf16x8 a = *(const bf16x8*)&Ws[(2 * w + t) * 16 + c][qd * 8];
#pragma unroll
                    for (int it = 0; it < 4; ++it) {
                        const bf16x8 b = *(const bf16x8*)&Xs[it * 16 + c][qd * 8];
                        acc[t * 4 + it] = __builtin_amdgcn_mfma_f32_16x16x32_bf16(a, b, acc[t * 4 + it], 0, 0, 0);
                    }
                }
            }
        }

        if (s < 2) {
            u16* Y = (s == 0) ? Yq : Yk;
#pragma unroll
            for (int nt = 0; nt < 8; ++nt) {
                const float bn = Bi[nt * 16 + c];
#pragma unroll
                for (int r = 0; r < 4; ++r)
                    Y[(size_t)(R0 + w * 16 + qd * 4 + r) * 128 + nt * 16 + c] = f2bf(acc[nt][r] + bn);
            }
        } else {
            const int bb = (pidx & 255) >> 3, il0 = R0 & 511;
#pragma unroll
            for (int t = 0; t < 2; ++t)
#pragma unroll
                for (int r = 0; r < 4; ++r) {
                    const int d = (2 * w + t) * 16 + qd * 4 + r;
                    const float bd = Bi[d];
#pragma unroll
                    for (int it = 0; it < 4; ++it)
                        YvT[(size_t)bb * 65536 + (size_t)d * 512 + il0 + it * 16 + c] =
                            f2bf(acc[t * 4 + it][r] + bd);
                }
        }
        return;
    }

    if (docanon) {
        // ---- mask_canon: 256 blocks, grid-stride 8 x 16 B per thread ----
        const int cb = blk - 1792;
        const bool i32src = (mode == 2) || (mode == 0 && *flag == 0);
#pragma unroll
        for (int it = 0; it < 8; ++it) {
            const size_t base = ((size_t)cb * 8 + it) * 4096 + (size_t)tid * 16;
            u32 wq[4];
            if (i32src) {
                const int* mi = (const int*)mask + base;
#pragma unroll
                for (int q = 0; q < 4; ++q) {
                    const int4 v = *(const int4*)(mi + q * 4);
                    wq[q] = (v.x ? 1u : 0u) | ((v.y ? 1u : 0u) << 8)
                          | ((v.z ? 1u : 0u) << 16) | ((v.w ? 1u : 0u) << 24);
                }
            } else {
                const u32x4 v = *(const u32x4*)((const unsigned char*)mask + base);
#pragma unroll
                for (int q = 0; q < 4; ++q) {
                    const u32 x = v[q];
                    wq[q] = (((x & 0x7F7F7F7Fu) + 0x7F7F7F7Fu) | x) >> 7 & 0x01010101u;
                }
            }
            *(u32x4*)(canonbuf + base) = (u32x4){wq[0], wq[1], wq[2], wq[3]};
        }
    }
}

// ---------------------------------------------------------------------------
// attn_mfma8 (round 8, proven): 8 waves, key-split 2 groups, reg-prefetch.
// ---------------------------------------------------------------------------
__global__ __launch_bounds__(512, 2) void attn_mfma8(
    const u16* __restrict__ qb, const u16* __restrict__ kb, const u16* __restrict__ vTb,
    const unsigned char* __restrict__ canon, const u16* __restrict__ biasb,
    float* __restrict__ out)
{
    __shared__ alignas(16) u16 Ks[2][64 * 136];
    __shared__ alignas(16) u16 Ps[2][64 * 72];
    __shared__ alignas(16) u16 Vs[2][128 * 72];
    __shared__ alignas(16) u16 Bs[2][64 * 72];
    __shared__ float redm[2][64];
    __shared__ float reds[2][64];

    const int tid  = threadIdx.x;
    const int g    = tid >> 8;
    const int gtid = tid & 255;
    const int wl   = (tid >> 6) & 3;
    const int lane = tid & 63;
    const int c    = lane & 15;
    const int qd   = lane >> 4;
    const int bb   = blockIdx.x & 31;
    const int it   = blockIdx.x >> 5;
    const int i0   = it * 64;

    bf16x8 qf[4];
    {
        const u16* qp = qb + ((size_t)bb * 512 + i0 + wl * 16 + c) * 128 + qd * 8;
#pragma unroll
        for (int kc = 0; kc < 4; ++kc) qf[kc] = *(const bf16x8*)(qp + kc * 32);
    }

    const int kr_ = gtid >> 2, ksg = gtid & 3;
    const u16* kbase = kb + ((size_t)bb * 512 + g * 256) * 128;
    {
        const u32x4* src = (const u32x4*)(kbase + (size_t)kr_ * 128 + ksg * 32);
        u32x4 k0 = src[0], k1 = src[1], k2 = src[2], k3 = src[3];
        u32x4* dst = (u32x4*)&Ks[g][kr_ * 136 + ksg * 32];
        dst[0] = k0; dst[1] = k1; dst[2] = k2; dst[3] = k3;
    }
    __syncthreads();

    f32x4 S[4][4];
#pragma unroll
    for (int jt = 0; jt < 4; ++jt)
#pragma unroll
        for (int jj = 0; jj < 4; ++jj) S[jt][jj] = (f32x4){0.f, 0.f, 0.f, 0.f};

#pragma unroll
    for (int jt = 0; jt < 4; ++jt) {
        u32x4 k0, k1, k2, k3;
        if (jt < 3) {
            const u32x4* src = (const u32x4*)(kbase + ((size_t)(jt + 1) * 64 + kr_) * 128 + ksg * 32);
            k0 = src[0]; k1 = src[1]; k2 = src[2]; k3 = src[3];
        }
#pragma unroll
        for (int kc = 0; kc < 4; ++kc) {
            const bf16x8 a = qf[kc];
#pragma unroll
            for (int jj = 0; jj < 4; ++jj) {
                const bf16x8 b = *(const bf16x8*)&Ks[g][(jj * 16 + c) * 136 + kc * 32 + qd * 8];
                S[jt][jj] = __builtin_amdgcn_mfma_f32_16x16x32_bf16(a, b, S[jt][jj], 0, 0, 0);
            }
        }
        if (jt < 3) {
            __syncthreads();
            u32x4* dst = (u32x4*)&Ks[g][kr_ * 136 + ksg * 32];
            dst[0] = k0; dst[1] = k1; dst[2] = k2; dst[3] = k3;
            __syncthreads();
        }
    }

    const int vd = gtid >> 1, vsg = gtid & 1;
    const int brw = gtid >> 2, bsg = gtid & 3;
    const u16* vbase = vTb + (size_t)bb * 65536;
    const u16* bbase = biasb + (size_t)bb * 262144;
    u32x4 vr0, vr1, vr2, vr3, br0, br1;
    {
        const u32x4* sv = (const u32x4*)(vbase + (size_t)vd * 512 + (g * 4) * 64 + vsg * 32);
        vr0 = sv[0]; vr1 = sv[1]; vr2 = sv[2]; vr3 = sv[3];
        const u32x4* sb = (const u32x4*)(bbase + (size_t)(i0 + brw) * 512 + (g * 4) * 64 + bsg * 16);
        br0 = sb[0]; br1 = sb[1];
    }

    const float sc = 0.08838834764831845f;
    float lm[4];
#pragma unroll
    for (int r = 0; r < 4; ++r) {
        const int lrow = wl * 16 + qd * 4 + r;
        const unsigned char* cp = canon + ((size_t)bb * 512 + i0 + lrow) * 512 + g * 256;
        float mx = -3.4e38f;
#pragma unroll
        for (int jt = 0; jt < 4; ++jt)
#pragma unroll
            for (int jj = 0; jj < 4; ++jj) {
                float s = S[jt][jj][r] * sc;
                if (cp[jt * 64 + jj * 16 + c]) s = 1e-9f;
                S[jt][jj][r] = s;
                mx = fmaxf(mx, s);
            }
#pragma unroll
        for (int o = 1; o < 16; o <<= 1) mx = fmaxf(mx, __shfl_xor(mx, o, 64));
        lm[r] = mx;
    }
    if (c == 0) {
#pragma unroll
        for (int r = 0; r < 4; ++r) redm[g][wl * 16 + qd * 4 + r] = lm[r];
    }
    __syncthreads();
    float ls[4];
#pragma unroll
    for (int r = 0; r < 4; ++r) {
        const int lrow = wl * 16 + qd * 4 + r;
        const float gmx = fmaxf(redm[0][lrow], redm[1][lrow]);
        float sm = 0.f;
#pragma unroll
        for (int jt = 0; jt < 4; ++jt)
#pragma unroll
            for (int jj = 0; jj < 4; ++jj) {
                const float e = __expf(S[jt][jj][r] - gmx);
                S[jt][jj][r] = e;
                sm += e;
            }
#pragma unroll
        for (int o = 1; o < 16; o <<= 1) sm += __shfl_xor(sm, o, 64);
        ls[r] = sm;
    }
    if (c == 0) {
#pragma unroll
        for (int r = 0; r < 4; ++r) reds[g][wl * 16 + qd * 4 + r] = ls[r];
    }
    __syncthreads();
    float inv_[4];
#pragma unroll
    for (int r = 0; r < 4; ++r) {
        const int lrow = wl * 16 + qd * 4 + r;
        inv_[r] = 1.0f / (reds[0][lrow] + reds[1][lrow]);
    }

    f32x4 O_[8];
#pragma unroll
    for (int ns = 0; ns < 8; ++ns) O_[ns] = (f32x4){0.f, 0.f, 0.f, 0.f};

#pragma unroll
    for (int jt = 0; jt < 4; ++jt) {
        __syncthreads();
        {
            u32x4* dv = (u32x4*)&Vs[g][vd * 72 + vsg * 32];
            dv[0] = vr0; dv[1] = vr1; dv[2] = vr2; dv[3] = vr3;
            u32x4* db = (u32x4*)&Bs[g][brw * 72 + bsg * 16];
            db[0] = br0; db[1] = br1;
        }
        __syncthreads();
        if (jt < 3) {
            const int tg = g * 4 + jt + 1;
            const u32x4* sv = (const u32x4*)(vbase + (size_t)vd * 512 + tg * 64 + vsg * 32);
            vr0 = sv[0]; vr1 = sv[1]; vr2 = sv[2]; vr3 = sv[3];
            const u32x4* sb = (const u32x4*)(bbase + (size_t)(i0 + brw) * 512 + tg * 64 + bsg * 16);
            br0 = sb[0]; br1 = sb[1];
        }
#pragma unroll
        for (int r = 0; r < 4; ++r) {
            const int lrow = wl * 16 + qd * 4 + r;
#pragma unroll
            for (int jj = 0; jj < 4; ++jj) {
                const float p = S[jt][jj][r] * inv_[r] + B2F(Bs[g][lrow * 72 + jj * 16 + c]);
                Ps[g][lrow * 72 + jj * 16 + c] = f2bf(p);
            }
        }
        __syncthreads();
#pragma unroll
        for (int kc = 0; kc < 2; ++kc) {
            const bf16x8 a = *(const bf16x8*)&Ps[g][(wl * 16 + c) * 72 + kc * 32 + qd * 8];
#pragma unroll
            for (int ns = 0; ns < 8; ++ns) {
                const bf16x8 b = *(const bf16x8*)&Vs[g][(ns * 16 + c) * 72 + kc * 32 + qd * 8];
                O_[ns] = __builtin_amdgcn_mfma_f32_16x16x32_bf16(a, b, O_[ns], 0, 0, 0);
            }
        }
    }

    __syncthreads();
    float* Oc = (float*)&Ks[0][0];
    if (g == 1) {
#pragma unroll
        for (int ns = 0; ns < 8; ++ns)
#pragma unroll
            for (int r = 0; r < 4; ++r)
                Oc[(wl * 16 + qd * 4 + r) * 128 + ns * 16 + c] = O_[ns][r];
    }
    __syncthreads();
    if (g == 0) {
#pragma unroll
        for (int ns = 0; ns < 8; ++ns)
#pragma unroll
            for (int r = 0; r < 4; ++r)
                Oc[(wl * 16 + qd * 4 + r) * 128 + ns * 16 + c] += O_[ns][r];
    }
    __syncthreads();
    {
        const int row = tid >> 3, sg = tid & 7;
        const float4* s4 = (const float4*)&Oc[row * 128 + sg * 16];
        float4* d4 = (float4*)(out + ((size_t)bb * 512 + i0 + row) * 128 + sg * 16);
        d4[0] = s4[0]; d4[1] = s4[1]; d4[2] = s4[2]; d4[3] = s4[3];
    }
}

// ---------------------------------------------------------------------------
extern "C" void kernel_launch(void* const* d_in, const int* in_sizes, int n_in,
                              void* d_out, int out_size, void* d_ws, size_t ws_size,
                              hipStream_t stream)
{
    const float* query = (const float*)d_in[0];
    const float* key_  = (const float*)d_in[1];
    const float* value = (const float*)d_in[2];
    const float* sf    = (const float*)d_in[3];
    const void*  mask  = d_in[4];
    const float* Wq  = (const float*)d_in[5];
    const float* bq  = (const float*)d_in[6];
    const float* Wk  = (const float*)d_in[7];
    const float* bk  = (const float*)d_in[8];
    const float* Wv  = (const float*)d_in[9];
    const float* bv  = (const float*)d_in[10];
    const float* Wb1 = (const float*)d_in[11];
    const float* bb1 = (const float*)d_in[12];
    const float* Wb2 = (const float*)d_in[13];
    const float* bb2 = (const float*)d_in[14];
    float* out = (float*)d_out;

    // ws layout
    char* w = (char*)d_ws;
    u32*   flag     = (u32*)(w);                                // 4 B
    unsigned char* canonbuf = (unsigned char*)(w + (1u << 20)); // 8 MiB
    u16*   qb    = (u16*)(w + (16u << 20));                     // 4 MiB
    u16*   kb    = (u16*)(w + (24u << 20));                     // 4 MiB
    u16*   vTb   = (u16*)(w + (32u << 20));                     // 4 MiB
    float* hT    = (float*)(w + (40u << 20));                   // 16 KiB (hT[m][b])
    u16*   biasb = (u16*)(w + (41u << 20));                     // 16 MiB
    u16*   WT    = (u16*)(w + (58u << 20));                     // 384 KiB

    // Mask dtype: mode 0 = runtime detect, 1 = bool bytes direct, 2 = i32.
    int mode = 0;
    if (n_in >= 15 && in_sizes[0] == 33554432) {
        if (in_sizes[4] == 8388608)       mode = 1;
        else if (in_sizes[4] == 33554432) mode = 2;
    }
    if (mode == 0) hipMemsetAsync(flag, 0, 4, stream);

    const int detN = (mode == 0) ? 128 : 0;
    prep<<<detN + 40, 256, 0, stream>>>(mask, flag, detN, Wq, Wk, Wv, WT,
                                        sf, Wb1, bb1, hT);

    const int docanon = (mode != 1) ? 1 : 0;
    mid<<<2048, 256, 0, stream>>>(query, key_, value, WT,
                                  bq, bk, bv, qb, kb, vTb,
                                  hT, Wb2, bb2, biasb,
                                  mask, flag, mode, docanon, canonbuf);

    const unsigned char* canon = (mode == 1) ? (const unsigned char*)mask : canonbuf;
    attn_mfma8<<<256, 512, 0, stream>>>(qb, kb, vTb, canon, biasb, out);
}